// Round 1
// baseline (295.929 us; speedup 1.0000x reference)
//
#include <hip/hip_runtime.h>
#include <hip/hip_bf16.h>
#include <stdint.h>

// Problem constants
#define NLAYERS 32
#define DSIZE   1024
#define OSIZE   1024
#define BATCH   32
#define SEQ     256

// ws layout (ints): [0]=ntiles; [16..272)=perm; [512 + 4*t ..]=tile{layer, rank_base, nranks, pad}
#define WS_PERM  16
#define WS_TILE  512
#define MAX_TILES 88   // sum ceil(cnt/4) <= 64 + 24 = 88

typedef __attribute__((ext_vector_type(8)))  short short8;
typedef __attribute__((ext_vector_type(16))) float f32x16;

#define LDSTRIDE 72   // shorts per LDS row (64 + 8 pad -> bank-group spread)
#define BK 64

__global__ void prep_kernel(const int* __restrict__ layer_idx, int* __restrict__ wsi) {
    __shared__ int cnt[NLAYERS];
    __shared__ int start_[NLAYERS];
    __shared__ int cursor[NLAYERS];
    const int t = threadIdx.x;
    if (t < NLAYERS) cnt[t] = 0;
    __syncthreads();
    int l = 0;
    if (t < SEQ) { l = layer_idx[t]; atomicAdd(&cnt[l], 1); }
    __syncthreads();
    if (t == 0) {
        int acc = 0;
        for (int i = 0; i < NLAYERS; ++i) { start_[i] = acc; cursor[i] = acc; acc += cnt[i]; }
    }
    __syncthreads();
    if (t < SEQ) {
        int r = atomicAdd(&cursor[l], 1);
        wsi[WS_PERM + r] = t;           // perm[rank] = s  (order within layer irrelevant)
    }
    if (t == 0) {
        int nt = 0;
        for (int i = 0; i < NLAYERS; ++i) {
            const int c = cnt[i];
            for (int j = 0; j < c; j += 4) {
                wsi[WS_TILE + nt*4 + 0] = i;
                wsi[WS_TILE + nt*4 + 1] = start_[i] + j;
                wsi[WS_TILE + nt*4 + 2] = (c - j < 4) ? (c - j) : 4;
                ++nt;
            }
        }
        wsi[0] = nt;
    }
}

// round-to-nearest fp32->bf16 pair pack: low16 = bf16(a), high16 = bf16(b)
static __device__ __forceinline__ unsigned pk2(float a, float b) {
    unsigned ua = __builtin_bit_cast(unsigned, a) + 0x8000u;
    unsigned ub = __builtin_bit_cast(unsigned, b) + 0x8000u;
    return __builtin_amdgcn_perm(ub, ua, 0x07060302u);  // {ua[2],ua[3],ub[2],ub[3]}
}

__global__ __launch_bounds__(256, 2) void gemm_kernel(
        const float* __restrict__ x, const float* __restrict__ wgt,
        const int* __restrict__ wsi, float* __restrict__ out) {
    const int ntiles = wsi[0];
    const int mt = blockIdx.y;
    if (mt >= ntiles) return;
    const int layer     = wsi[WS_TILE + mt*4 + 0];
    const int rank_base = wsi[WS_TILE + mt*4 + 1];
    const int nranks    = wsi[WS_TILE + mt*4 + 2];
    const int ntile     = blockIdx.x;   // 0..7 -> o block of 128

    __shared__ __align__(16) short ldsA[128 * LDSTRIDE];
    __shared__ __align__(16) short ldsB[128 * LDSTRIDE];

    const int t     = threadIdx.x;
    const int row   = t >> 1;     // 0..127 staging row
    const int khalf = t & 1;      // covers k-offset 0 / 32 within BK

    // A staging row -> (rank, b, s); roff uniform per wave (rows 32w..32w+31)
    const int  roffA  = row >> 5;
    const bool validA = roffA < nranks;
    const int  sA     = validA ? wsi[WS_PERM + rank_base + roffA] : 0;
    const int  bA     = row & 31;
    const float* aptr = x + (((size_t)(bA * SEQ + sA)) << 10) + khalf * 32;
    const int  oRow   = ntile * 128 + row;
    const float* bptr = wgt + (((size_t)((layer << 10) + oRow)) << 10) + khalf * 32;

    float4 ra[8], rb[8];
    auto load_step = [&](int kk) {
        const float* ap = aptr + kk;
        const float* bp = bptr + kk;
        if (validA) {
            #pragma unroll
            for (int i = 0; i < 8; ++i) ra[i] = *(const float4*)(ap + i*4);
        } else {
            #pragma unroll
            for (int i = 0; i < 8; ++i) ra[i] = make_float4(0.f, 0.f, 0.f, 0.f);
        }
        #pragma unroll
        for (int i = 0; i < 8; ++i) rb[i] = *(const float4*)(bp + i*4);
    };

    // compute-side mapping
    const int lane = t & 63;
    const int wv   = t >> 6;
    const int wm   = (wv & 1) * 64;   // wave row base
    const int wn   = (wv >> 1) * 64;  // wave col base
    const int l31  = lane & 31;
    const int lh   = lane >> 5;

    f32x16 acc[2][2];
    #pragma unroll
    for (int mi = 0; mi < 2; ++mi)
        #pragma unroll
        for (int ni = 0; ni < 2; ++ni)
            #pragma unroll
            for (int r = 0; r < 16; ++r) acc[mi][ni][r] = 0.f;

    const short* pA0 = &ldsA[(wm + l31) * LDSTRIDE + lh * 8];
    const short* pB0 = &ldsB[(wn + l31) * LDSTRIDE + lh * 8];
    const int ldsW = row * LDSTRIDE + khalf * 32;

    load_step(0);
    #pragma unroll 1
    for (int kk = 0; kk < DSIZE; kk += BK) {
        __syncthreads();   // previous compute done reading LDS
        #pragma unroll
        for (int i = 0; i < 4; ++i) {
            uint4 v;
            v.x = pk2(ra[2*i].x,   ra[2*i].y);
            v.y = pk2(ra[2*i].z,   ra[2*i].w);
            v.z = pk2(ra[2*i+1].x, ra[2*i+1].y);
            v.w = pk2(ra[2*i+1].z, ra[2*i+1].w);
            *(uint4*)&ldsA[ldsW + i*8] = v;
        }
        #pragma unroll
        for (int i = 0; i < 4; ++i) {
            uint4 v;
            v.x = pk2(rb[2*i].x,   rb[2*i].y);
            v.y = pk2(rb[2*i].z,   rb[2*i].w);
            v.z = pk2(rb[2*i+1].x, rb[2*i+1].y);
            v.w = pk2(rb[2*i+1].z, rb[2*i+1].w);
            *(uint4*)&ldsB[ldsW + i*8] = v;
        }
        __syncthreads();
        if (kk + BK < DSIZE) load_step(kk + BK);  // prefetch overlaps MFMA below
        #pragma unroll
        for (int sub = 0; sub < 4; ++sub) {       // 4 x (K=16) sub-steps
            short8 a0 = *(const short8*)(pA0 + sub*16);
            short8 a1 = *(const short8*)(pA0 + 32*LDSTRIDE + sub*16);
            short8 b0 = *(const short8*)(pB0 + sub*16);
            short8 b1 = *(const short8*)(pB0 + 32*LDSTRIDE + sub*16);
            acc[0][0] = __builtin_amdgcn_mfma_f32_32x32x16_bf16(a0, b0, acc[0][0], 0, 0, 0);
            acc[0][1] = __builtin_amdgcn_mfma_f32_32x32x16_bf16(a0, b1, acc[0][1], 0, 0, 0);
            acc[1][0] = __builtin_amdgcn_mfma_f32_32x32x16_bf16(a1, b0, acc[1][0], 0, 0, 0);
            acc[1][1] = __builtin_amdgcn_mfma_f32_32x32x16_bf16(a1, b1, acc[1][1], 0, 0, 0);
        }
    }

    // epilogue: C/D layout col = lane&31, row = (reg&3) + 8*(reg>>2) + 4*(lane>>5)
    #pragma unroll
    for (int mi = 0; mi < 2; ++mi) {
        const int roff = (wv & 1) * 2 + mi;     // tile-row group = rank offset (uniform/frag)
        if (roff >= nranks) continue;
        const int s = wsi[WS_PERM + rank_base + roff];
        #pragma unroll
        for (int ni = 0; ni < 2; ++ni) {
            const int ocol = ntile * 128 + wn + ni * 32 + l31;
            #pragma unroll
            for (int r = 0; r < 16; ++r) {
                const int brow = (r & 3) + 8 * (r >> 2) + 4 * lh;  // = b
                out[(((size_t)(brow * SEQ + s)) << 10) + ocol] = acc[mi][ni][r];
            }
        }
    }
}

extern "C" void kernel_launch(void* const* d_in, const int* in_sizes, int n_in,
                              void* d_out, int out_size, void* d_ws, size_t ws_size,
                              hipStream_t stream) {
    const float* x         = (const float*)d_in[0];
    const int*   layer_idx = (const int*)  d_in[1];
    const float* weight    = (const float*)d_in[2];
    float* out = (float*)d_out;
    int*   wsi = (int*)d_ws;

    prep_kernel<<<1, 256, 0, stream>>>(layer_idx, wsi);
    gemm_kernel<<<dim3(8, MAX_TILES), 256, 0, stream>>>(x, weight, wsi, out);
}

// Round 2
// 259.779 us; speedup vs baseline: 1.1392x; 1.1392x over previous
//
#include <hip/hip_runtime.h>
#include <hip/hip_bf16.h>
#include <stdint.h>

// Problem constants
#define NLAYERS 32
#define DSIZE   1024
#define OSIZE   1024
#define BATCH   32
#define SEQ     256

// ws layout (ints): [0]=ntiles; [16..272)=perm; [512 + 4*t ..]=tile{layer, rank_base, nranks, pad}
#define WS_PERM  16
#define WS_TILE  512
#define MAX_TILES 88   // sum ceil(cnt/4) <= 64 + 24 = 88

typedef __attribute__((ext_vector_type(8)))  short short8;
typedef __attribute__((ext_vector_type(16))) float f32x16;

#define LDSTRIDE 72   // shorts per LDS row (64 + 8 pad; 144 B = 16B-aligned rows)
#define BK 64

__global__ void prep_kernel(const int* __restrict__ layer_idx, int* __restrict__ wsi) {
    __shared__ int cnt[NLAYERS];
    __shared__ int start_[NLAYERS];
    __shared__ int cursor[NLAYERS];
    const int t = threadIdx.x;
    if (t < NLAYERS) cnt[t] = 0;
    __syncthreads();
    int l = 0;
    if (t < SEQ) { l = layer_idx[t]; atomicAdd(&cnt[l], 1); }
    __syncthreads();
    if (t == 0) {
        int acc = 0;
        for (int i = 0; i < NLAYERS; ++i) { start_[i] = acc; cursor[i] = acc; acc += cnt[i]; }
    }
    __syncthreads();
    if (t < SEQ) {
        int r = atomicAdd(&cursor[l], 1);
        wsi[WS_PERM + r] = t;           // perm[rank] = s  (order within layer irrelevant)
    }
    if (t == 0) {
        int nt = 0;
        for (int i = 0; i < NLAYERS; ++i) {
            const int c = cnt[i];
            for (int j = 0; j < c; j += 4) {
                wsi[WS_TILE + nt*4 + 0] = i;
                wsi[WS_TILE + nt*4 + 1] = start_[i] + j;
                wsi[WS_TILE + nt*4 + 2] = (c - j < 4) ? (c - j) : 4;
                ++nt;
            }
        }
        wsi[0] = nt;
    }
}

// round-to-nearest fp32->bf16 pair pack: low16 = bf16(a), high16 = bf16(b)
static __device__ __forceinline__ unsigned pk2(float a, float b) {
    unsigned ua = __builtin_bit_cast(unsigned, a) + 0x8000u;
    unsigned ub = __builtin_bit_cast(unsigned, b) + 0x8000u;
    return __builtin_amdgcn_perm(ub, ua, 0x07060302u);  // {ua[2],ua[3],ub[2],ub[3]}
}

__global__ __launch_bounds__(256, 2) void gemm_kernel(
        const float* __restrict__ x, const float* __restrict__ wgt,
        const int* __restrict__ wsi, float* __restrict__ out) {
    const int ntiles = wsi[0];
    const int mt = blockIdx.y;
    if (mt >= ntiles) return;
    const int layer     = wsi[WS_TILE + mt*4 + 0];
    const int rank_base = wsi[WS_TILE + mt*4 + 1];
    const int nranks    = wsi[WS_TILE + mt*4 + 2];
    const int ntile     = blockIdx.x;   // 0..7 -> o block of 128

    __shared__ __align__(16) short ldsA[128 * LDSTRIDE];
    __shared__ __align__(16) short ldsB[128 * LDSTRIDE];

    const int t     = threadIdx.x;
    // ---- coalesced staging mapping: wave = 4 rows x 16 lanes x 16B (4 x 256B segments)
    const int c4    = (t & 15) * 4;   // float column within the 64-wide k-slab
    const int rbase = t >> 4;         // 0..15; pass p covers row = rbase + 16*p

    // pass p -> row = rbase + 16p; rank offset roff = p>>1 (wave-uniform), b = rbase + 16*(p&1)
    int svals[2];  // only roff 0..3 used; svals[j] for j = p>>1
    bool svalid[4];
    int sv[4];
    #pragma unroll
    for (int j = 0; j < 4; ++j) {
        svalid[j] = (j < nranks);
        sv[j] = svalid[j] ? wsi[WS_PERM + rank_base + j] : 0;
    }
    (void)svals;

    const float* aptr[8];
    #pragma unroll
    for (int p = 0; p < 8; ++p) {
        const int roff = p >> 1;
        const int b    = rbase + ((p & 1) << 4);
        aptr[p] = x + (((size_t)(b * SEQ + sv[roff])) << 10) + c4;
    }
    const float* bbase = wgt + (((size_t)((layer << 10) + ntile * 128 + rbase)) << 10) + c4;

    float4 ra[8], rb[8];
    auto load_step = [&](int kk) {
        #pragma unroll
        for (int p = 0; p < 8; ++p) {
            if (svalid[p >> 1]) ra[p] = *(const float4*)(aptr[p] + kk);
            else                ra[p] = make_float4(0.f, 0.f, 0.f, 0.f);
            rb[p] = *(const float4*)(bbase + ((size_t)p << 14) + kk);  // +p*16 rows
        }
    };

    // compute-side mapping
    const int lane = t & 63;
    const int wv   = t >> 6;
    const int wm   = (wv & 1) * 64;   // wave row base
    const int wn   = (wv >> 1) * 64;  // wave col base
    const int l31  = lane & 31;
    const int lh   = lane >> 5;

    f32x16 acc[2][2];
    #pragma unroll
    for (int mi = 0; mi < 2; ++mi)
        #pragma unroll
        for (int ni = 0; ni < 2; ++ni)
            #pragma unroll
            for (int r = 0; r < 16; ++r) acc[mi][ni][r] = 0.f;

    const short* pA0 = &ldsA[(wm + l31) * LDSTRIDE + lh * 8];
    const short* pB0 = &ldsB[(wn + l31) * LDSTRIDE + lh * 8];

    load_step(0);
    #pragma unroll 1
    for (int kk = 0; kk < DSIZE; kk += BK) {
        __syncthreads();   // previous compute done reading LDS
        #pragma unroll
        for (int p = 0; p < 8; ++p) {
            const int row = rbase + 16 * p;
            uint2 va, vb;
            va.x = pk2(ra[p].x, ra[p].y);
            va.y = pk2(ra[p].z, ra[p].w);
            vb.x = pk2(rb[p].x, rb[p].y);
            vb.y = pk2(rb[p].z, rb[p].w);
            *(uint2*)&ldsA[row * LDSTRIDE + c4] = va;
            *(uint2*)&ldsB[row * LDSTRIDE + c4] = vb;
        }
        __syncthreads();
        if (kk + BK < DSIZE) load_step(kk + BK);  // prefetch overlaps MFMA below
        #pragma unroll
        for (int sub = 0; sub < 4; ++sub) {       // 4 x (K=16) sub-steps
            short8 a0 = *(const short8*)(pA0 + sub*16);
            short8 a1 = *(const short8*)(pA0 + 32*LDSTRIDE + sub*16);
            short8 b0 = *(const short8*)(pB0 + sub*16);
            short8 b1 = *(const short8*)(pB0 + 32*LDSTRIDE + sub*16);
            acc[0][0] = __builtin_amdgcn_mfma_f32_32x32x16_bf16(a0, b0, acc[0][0], 0, 0, 0);
            acc[0][1] = __builtin_amdgcn_mfma_f32_32x32x16_bf16(a0, b1, acc[0][1], 0, 0, 0);
            acc[1][0] = __builtin_amdgcn_mfma_f32_32x32x16_bf16(a1, b0, acc[1][0], 0, 0, 0);
            acc[1][1] = __builtin_amdgcn_mfma_f32_32x32x16_bf16(a1, b1, acc[1][1], 0, 0, 0);
        }
    }

    // epilogue: C/D layout col = lane&31, row = (reg&3) + 8*(reg>>2) + 4*(lane>>5)
    #pragma unroll
    for (int mi = 0; mi < 2; ++mi) {
        const int roff = (wv & 1) * 2 + mi;     // tile-row group = rank offset
        if (roff >= nranks) continue;
        const int s = wsi[WS_PERM + rank_base + roff];
        #pragma unroll
        for (int ni = 0; ni < 2; ++ni) {
            const int ocol = ntile * 128 + wn + ni * 32 + l31;
            #pragma unroll
            for (int r = 0; r < 16; ++r) {
                const int brow = (r & 3) + 8 * (r >> 2) + 4 * lh;  // = b
                out[(((size_t)(brow * SEQ + s)) << 10) + ocol] = acc[mi][ni][r];
            }
        }
    }
}

extern "C" void kernel_launch(void* const* d_in, const int* in_sizes, int n_in,
                              void* d_out, int out_size, void* d_ws, size_t ws_size,
                              hipStream_t stream) {
    const float* x         = (const float*)d_in[0];
    const int*   layer_idx = (const int*)  d_in[1];
    const float* weight    = (const float*)d_in[2];
    float* out = (float*)d_out;
    int*   wsi = (int*)d_ws;

    prep_kernel<<<1, 256, 0, stream>>>(layer_idx, wsi);
    gemm_kernel<<<dim3(8, MAX_TILES), 256, 0, stream>>>(x, weight, wsi, out);
}

// Round 3
// 251.443 us; speedup vs baseline: 1.1769x; 1.0332x over previous
//
#include <hip/hip_runtime.h>
#include <hip/hip_bf16.h>
#include <stdint.h>

// Problem constants
#define NLAYERS 32
#define DSIZE   1024
#define OSIZE   1024
#define BATCH   32
#define SEQ     256

// ws layout (ints): [0]=ntiles; [16..272)=perm; [512 + 4*t ..]=tile{layer, rank_base, nranks, pad}
#define WS_PERM  16
#define WS_TILE  512
#define MAX_TILES 88   // sum ceil(cnt/4) <= 64 + 24 = 88

typedef __attribute__((ext_vector_type(8)))  short short8;
typedef __attribute__((ext_vector_type(16))) float f32x16;

#define LDSTRIDE 72   // shorts per LDS row (64 + 8 pad; 144 B = 16B-aligned rows)
#define BK 64
#define NSPLIT 16     // o-dim tiles of 64 -> grid 16 x 88 = 1408 blocks (~5.5/CU)

__global__ void prep_kernel(const int* __restrict__ layer_idx, int* __restrict__ wsi) {
    __shared__ int cnt[NLAYERS];
    __shared__ int start_[NLAYERS];
    __shared__ int cursor[NLAYERS];
    const int t = threadIdx.x;
    if (t < NLAYERS) cnt[t] = 0;
    __syncthreads();
    int l = 0;
    if (t < SEQ) { l = layer_idx[t]; atomicAdd(&cnt[l], 1); }
    __syncthreads();
    if (t == 0) {
        int acc = 0;
        for (int i = 0; i < NLAYERS; ++i) { start_[i] = acc; cursor[i] = acc; acc += cnt[i]; }
    }
    __syncthreads();
    if (t < SEQ) {
        int r = atomicAdd(&cursor[l], 1);
        wsi[WS_PERM + r] = t;           // perm[rank] = s  (order within layer irrelevant)
    }
    if (t == 0) {
        int nt = 0;
        for (int i = 0; i < NLAYERS; ++i) {
            const int c = cnt[i];
            for (int j = 0; j < c; j += 4) {
                wsi[WS_TILE + nt*4 + 0] = i;
                wsi[WS_TILE + nt*4 + 1] = start_[i] + j;
                wsi[WS_TILE + nt*4 + 2] = (c - j < 4) ? (c - j) : 4;
                ++nt;
            }
        }
        wsi[0] = nt;
    }
}

// round-to-nearest fp32->bf16 pair pack: low16 = bf16(a), high16 = bf16(b)
static __device__ __forceinline__ unsigned pk2(float a, float b) {
    unsigned ua = __builtin_bit_cast(unsigned, a) + 0x8000u;
    unsigned ub = __builtin_bit_cast(unsigned, b) + 0x8000u;
    return __builtin_amdgcn_perm(ub, ua, 0x07060302u);  // {ua[2],ua[3],ub[2],ub[3]}
}

// Tile: 128 m-rows (4 ranks x 32 batch) x 64 o-cols, BK=64, 4 waves.
// Wave wv computes rows [32*wv, 32*wv+32) x all 64 cols -> rank roff == wv.
__global__ __launch_bounds__(256, 3) void gemm_kernel(
        const float* __restrict__ x, const float* __restrict__ wgt,
        const int* __restrict__ wsi, float* __restrict__ out) {
    const int ntiles = wsi[0];
    const int mt = blockIdx.y;
    if (mt >= ntiles) return;
    const int layer     = wsi[WS_TILE + mt*4 + 0];
    const int rank_base = wsi[WS_TILE + mt*4 + 1];
    const int nranks    = wsi[WS_TILE + mt*4 + 2];
    const int ntile     = blockIdx.x;   // 0..15 -> o block of 64

    __shared__ __align__(16) short ldsA[128 * LDSTRIDE];
    __shared__ __align__(16) short ldsB[64 * LDSTRIDE];

    const int t     = threadIdx.x;
    // ---- coalesced staging: wave = 4 rows x 16 lanes x 16B (4 x 256B segments/instr)
    const int c4    = (t & 15) * 4;   // float (== bf16-short) column within 64-wide k-slab
    const int rbase = t >> 4;         // 0..15; pass p covers row = rbase + 16*p

    bool svalid[4];
    int  sv[4];
    #pragma unroll
    for (int j = 0; j < 4; ++j) {
        svalid[j] = (j < nranks);
        sv[j] = svalid[j] ? wsi[WS_PERM + rank_base + j] : 0;
    }

    // A rows: row = rbase + 16p (p=0..7) -> rank roff = p>>1, batch b = rbase + 16*(p&1)
    const float* aptr[8];
    #pragma unroll
    for (int p = 0; p < 8; ++p) {
        const int roff = p >> 1;
        const int b    = rbase + ((p & 1) << 4);
        aptr[p] = x + (((size_t)(b * SEQ + sv[roff])) << 10) + c4;
    }
    // B rows: orow = ntile*64 + rbase + 16p (p=0..3)
    const float* bbase = wgt + (((size_t)((layer << 10) + ntile * 64 + rbase)) << 10) + c4;

    float4 ra[8], rb[4];
    auto load_step = [&](int kk) {
        #pragma unroll
        for (int p = 0; p < 8; ++p) {
            if (svalid[p >> 1]) ra[p] = *(const float4*)(aptr[p] + kk);
            else                ra[p] = make_float4(0.f, 0.f, 0.f, 0.f);
        }
        #pragma unroll
        for (int p = 0; p < 4; ++p)
            rb[p] = *(const float4*)(bbase + ((size_t)p << 14) + kk);  // +p*16 rows
    };

    // compute-side mapping
    const int lane = t & 63;
    const int wv   = t >> 6;
    const int wm   = wv * 32;         // wave row base == rank wv
    const int l31  = lane & 31;
    const int lh   = lane >> 5;

    f32x16 acc[2];
    #pragma unroll
    for (int ni = 0; ni < 2; ++ni)
        #pragma unroll
        for (int r = 0; r < 16; ++r) acc[ni][r] = 0.f;

    const short* pA0 = &ldsA[(wm + l31) * LDSTRIDE + lh * 8];
    const short* pB0 = &ldsB[l31 * LDSTRIDE + lh * 8];

    load_step(0);
    #pragma unroll 1
    for (int kk = 0; kk < DSIZE; kk += BK) {
        __syncthreads();   // previous compute done reading LDS
        #pragma unroll
        for (int p = 0; p < 8; ++p) {
            const int row = rbase + 16 * p;
            uint2 va;
            va.x = pk2(ra[p].x, ra[p].y);
            va.y = pk2(ra[p].z, ra[p].w);
            *(uint2*)&ldsA[row * LDSTRIDE + c4] = va;
        }
        #pragma unroll
        for (int p = 0; p < 4; ++p) {
            const int row = rbase + 16 * p;
            uint2 vb;
            vb.x = pk2(rb[p].x, rb[p].y);
            vb.y = pk2(rb[p].z, rb[p].w);
            *(uint2*)&ldsB[row * LDSTRIDE + c4] = vb;
        }
        __syncthreads();
        if (kk + BK < DSIZE) load_step(kk + BK);  // prefetch overlaps MFMA below
        #pragma unroll
        for (int sub = 0; sub < 4; ++sub) {       // 4 x (K=16) sub-steps
            short8 a0 = *(const short8*)(pA0 + sub*16);
            short8 b0 = *(const short8*)(pB0 + sub*16);
            short8 b1 = *(const short8*)(pB0 + 32*LDSTRIDE + sub*16);
            acc[0] = __builtin_amdgcn_mfma_f32_32x32x16_bf16(a0, b0, acc[0], 0, 0, 0);
            acc[1] = __builtin_amdgcn_mfma_f32_32x32x16_bf16(a0, b1, acc[1], 0, 0, 0);
        }
    }

    // epilogue: C/D layout col = lane&31, row = (reg&3) + 8*(reg>>2) + 4*(lane>>5)
    if (wv < nranks) {
        const int s = wsi[WS_PERM + rank_base + wv];
        #pragma unroll
        for (int ni = 0; ni < 2; ++ni) {
            const int ocol = ntile * 64 + ni * 32 + l31;
            #pragma unroll
            for (int r = 0; r < 16; ++r) {
                const int brow = (r & 3) + 8 * (r >> 2) + 4 * lh;  // = batch b
                out[(((size_t)(brow * SEQ + s)) << 10) + ocol] = acc[ni][r];
            }
        }
    }
}

extern "C" void kernel_launch(void* const* d_in, const int* in_sizes, int n_in,
                              void* d_out, int out_size, void* d_ws, size_t ws_size,
                              hipStream_t stream) {
    const float* x         = (const float*)d_in[0];
    const int*   layer_idx = (const int*)  d_in[1];
    const float* weight    = (const float*)d_in[2];
    float* out = (float*)d_out;
    int*   wsi = (int*)d_ws;

    prep_kernel<<<1, 256, 0, stream>>>(layer_idx, wsi);
    gemm_kernel<<<dim3(NSPLIT, MAX_TILES), 256, 0, stream>>>(x, weight, wsi, out);
}